// Round 17
// baseline (725.804 us; speedup 1.0000x reference)
//
#include <hip/hip_runtime.h>

#define B_   32
#define C_   256
#define N_   1024
#define L_   12
#define H_   8
#define DK_  32
#define NL_  12288
#define CNL_ 3145728
#define ND_  32768
#define HLN_ 98304
#define SCALE_ 0.17677669529663687f

typedef _Float16 half8 __attribute__((ext_vector_type(8)));
typedef _Float16 half4 __attribute__((ext_vector_type(4)));
typedef float f32x4 __attribute__((ext_vector_type(4)));

__device__ __forceinline__ int div12(int s) { return (int)(((unsigned)s * 43691u) >> 19); }
// bank-spreading chunk swizzle for conv_out's Xt (bijective, banks spread per instr)
__device__ __forceinline__ int fsw(int c) { return c ^ (((c >> 4) & 1) << 2) ^ ((c >> 6) & 3); }

// ---- P: one-time fp32 -> fp16 weight conversion into FRAGMENT-ORDER layout --
__global__ __launch_bounds__(256) void k_prep(const float* __restrict__ wq,
    const float* __restrict__ wv, const float* __restrict__ cw,
    _Float16* __restrict__ Wfrag, _Float16* __restrict__ Cfrag) {
    const int gid = blockIdx.x * 256 + threadIdx.x;   // grid 96 -> 24576
    if (gid < 16384) {
        const int kb = gid >> 11, r = gid & 2047;
        const int mt = r >> 6, o = (r >> 4) & 3, lo = r & 15;
        const int m = mt * 16 + lo;
        const float* src = (m < 256 ? wq + (size_t)m * 256 : wv + (size_t)(m - 256) * 256)
                           + kb * 32 + o * 8;
        f32x4 a0 = *(const f32x4*)src, a1 = *(const f32x4*)(src + 4);
        half8 h;
#pragma unroll
        for (int i = 0; i < 4; ++i) { h[i] = (_Float16)a0[i]; h[4 + i] = (_Float16)a1[i]; }
        *(half8*)(Wfrag + (size_t)gid * 8) = h;
    } else {
        const int c = gid - 16384;                    // < 8192
        const int kb = c >> 10, r = c & 1023;
        const int mt = r >> 6, o = (r >> 4) & 3, lo = r & 15;
        const int m = mt * 16 + lo;
        const float* src = cw + (size_t)m * 256 + kb * 32 + o * 8;
        f32x4 a0 = *(const f32x4*)src, a1 = *(const f32x4*)(src + 4);
        half8 h;
#pragma unroll
        for (int i = 0; i < 4; ++i) { h[i] = (_Float16)a0[i]; h[4 + i] = (_Float16)a1[i]; }
        *(half8*)(Cfrag + (size_t)c * 8) = h;
    }
}

// ---- K0: softmax over DK -> ksT[hl][x][n]; LDS transpose, coalesced stores --
__global__ __launch_bounds__(256) void k_key_softmax(const float* __restrict__ sb,
                                                     _Float16* __restrict__ ksT) {
    __shared__ _Float16 smT[32 * 260];
    const int t = threadIdx.x;
    const int row = blockIdx.x * 256 + t;
    const f32x4* src = (const f32x4*)(sb + (size_t)row * DK_);
    float v[DK_];
#pragma unroll
    for (int i = 0; i < 8; i++) {
        f32x4 t4 = src[i];
        v[4*i+0] = t4[0]; v[4*i+1] = t4[1]; v[4*i+2] = t4[2]; v[4*i+3] = t4[3];
    }
    float m = v[0];
#pragma unroll
    for (int i = 1; i < DK_; i++) m = fmaxf(m, v[i]);
    float s = 0.f;
#pragma unroll
    for (int i = 0; i < DK_; i++) { v[i] = __expf((v[i] - m) * SCALE_); s += v[i]; }
    const float inv = 1.f / s;
#pragma unroll
    for (int i = 0; i < DK_; i++) smT[i * 260 + t] = (_Float16)(v[i] * inv);
    __syncthreads();
    const int x = t >> 3, off = (t & 7) * 32;
    const int base = blockIdx.x * 256;
    const int hl = base >> 10, nb = base & 1023;
    _Float16* dst = ksT + (size_t)hl * ND_ + (size_t)x * 1024 + nb + off;
    const _Float16* srcT = &smT[x * 260 + off];
#pragma unroll
    for (int k = 0; k < 4; ++k)
        *(half8*)(dst + k * 8) = *(const half8*)(srcT + k * 8);
}

// ------- K1: merged q+v conv; M=512, W in REGISTERS, S=64/iter --------------
// grid (16 = sgrp, 32 = b), 512 thr. 12 tiles of 64 spatial per block.
__global__ __launch_bounds__(512, 2) void k_conv_qv(
    const float* __restrict__ x, const _Float16* __restrict__ Wfrag,
    const float* __restrict__ bqp, const float* __restrict__ bvp,
    _Float16* __restrict__ qh, _Float16* __restrict__ vh)
{
    __shared__ __align__(16) _Float16 Xl[2][16384];  // 2 buf x 4 subtiles x 4096

    const int t = threadIdx.x;
    const int sgrp = blockIdx.x;            // 0..15
    const int b = blockIdx.y;
    const int sbase = sgrp * 768;
    const int w = t >> 6, lane = t & 63;
    const int lo = lane & 15, hi = lane >> 4;

    // A-fragments resident in registers: wave w owns rows w*64 .. w*64+63
    half8 af[8][4];
#pragma unroll
    for (int kb = 0; kb < 8; ++kb)
#pragma unroll
        for (int m = 0; m < 4; ++m)
            af[kb][m] = *(const half8*)(Wfrag +
                ((size_t)kb*2048 + (size_t)(w*4 + m)*64 + lane) * 8);

    // X staging maps (write side), per subtile
    const int xch = t >> 1, xsh = (t & 1) * 8;      // channel, spatial half
    const int g = xch >> 3, elem = xch & 7;
    const int wb = g*128 + elem;                     // half-index base
    const int sx = xsh ^ ((g & 7) << 1) ^ (xsh >> 3);
    const float* px = x + (size_t)b * CNL_ + (size_t)xch * NL_ + sbase + xsh;

    // read-side swizzle base (per subtile)
    const int base_r = hi*128 + ((lo ^ (hi*2) ^ ((lo & 8) >> 3)) << 3);

    // prologue: tile0 (4 subtiles) -> LDS buf0; tile1 -> regs
    f32x4 c[8];
#pragma unroll
    for (int u = 0; u < 4; ++u) {
        c[2*u]   = *(const f32x4*)(px + u*16);
        c[2*u+1] = *(const f32x4*)(px + u*16 + 4);
    }
#pragma unroll
    for (int u = 0; u < 4; ++u)
#pragma unroll
        for (int k = 0; k < 4; ++k) {
            Xl[0][u*4096 + wb + (((k  ) ^ sx) << 3)] = (_Float16)c[2*u][k];
            Xl[0][u*4096 + wb + (((k+4) ^ sx) << 3)] = (_Float16)c[2*u+1][k];
        }
#pragma unroll
    for (int u = 0; u < 4; ++u) {
        c[2*u]   = *(const f32x4*)(px + 64 + u*16);
        c[2*u+1] = *(const f32x4*)(px + 64 + u*16 + 4);
    }

    for (int i = 0; i < 12; ++i) {
        asm volatile("s_waitcnt lgkmcnt(0)" ::: "memory");
        __builtin_amdgcn_s_barrier();
        __builtin_amdgcn_sched_barrier(0);
        const _Float16* Xc = Xl[i & 1];
        f32x4 acc[4][4] = {};
#pragma unroll
        for (int kb = 0; kb < 8; ++kb) {
            const int ro = kb*512 + (base_r ^ ((kb & 1) << 6));
            half8 bf0 = *(const half8*)&Xc[ro];
            half8 bf1 = *(const half8*)&Xc[4096  + ro];
            half8 bf2 = *(const half8*)&Xc[8192  + ro];
            half8 bf3 = *(const half8*)&Xc[12288 + ro];
#pragma unroll
            for (int m = 0; m < 4; ++m) {
                acc[m][0] = __builtin_amdgcn_mfma_f32_16x16x32_f16(af[kb][m], bf0, acc[m][0], 0, 0, 0);
                acc[m][1] = __builtin_amdgcn_mfma_f32_16x16x32_f16(af[kb][m], bf1, acc[m][1], 0, 0, 0);
                acc[m][2] = __builtin_amdgcn_mfma_f32_16x16x32_f16(af[kb][m], bf2, acc[m][2], 0, 0, 0);
                acc[m][3] = __builtin_amdgcn_mfma_f32_16x16x32_f16(af[kb][m], bf3, acc[m][3], 0, 0, 0);
            }
        }
        // write tile i+1 (regs loaded one iter ago), then issue tile i+2 loads
        if (i < 11) {
            _Float16* Xn = Xl[(i + 1) & 1];
#pragma unroll
            for (int u = 0; u < 4; ++u)
#pragma unroll
                for (int k = 0; k < 4; ++k) {
                    Xn[u*4096 + wb + (((k  ) ^ sx) << 3)] = (_Float16)c[2*u][k];
                    Xn[u*4096 + wb + (((k+4) ^ sx) << 3)] = (_Float16)c[2*u+1][k];
                }
            if (i < 10) {
                const float* p = px + (size_t)(i + 2) * 64;
#pragma unroll
                for (int u = 0; u < 4; ++u) {
                    c[2*u]   = *(const f32x4*)(p + u*16);
                    c[2*u+1] = *(const f32x4*)(p + u*16 + 4);
                }
            }
        }
        // epilogue for tile i: bias (loaded here) + relu + fp16, direct stores
        const float* bsel = (w >= 4) ? bvp : bqp;
        _Float16* dst0 = (w >= 4) ? vh : qh;
#pragma unroll
        for (int u = 0; u < 4; ++u) {
            const int sg = sbase + i*64 + u*16 + lo;
            const int n = div12(sg), l = sg - n*12;
#pragma unroll
            for (int m = 0; m < 4; ++m) {
                const int o = (w*4 + m)*16 + hi*4;
                const int ol = o & 255;
                const f32x4 bbv = *(const f32x4*)(bsel + ol);
                half4 hh;
#pragma unroll
                for (int r = 0; r < 4; ++r) hh[r] = (_Float16)fmaxf(acc[m][u][r] + bbv[r], 0.f);
                *(half4*)(dst0 + ((size_t)(b*8 + (ol >> 5))*12 + l)*ND_ + (size_t)n*32 + (ol & 31)) = hh;
            }
        }
    }
}

// ---- K2: kvT[b,h,l][y][x] = sum_n V[n][y]*K[n][x] via MFMA ------------------
__global__ __launch_bounds__(256) void k_kv(const _Float16* __restrict__ ksT,
    const _Float16* __restrict__ v, _Float16* __restrict__ kvT) {
    __shared__ float red[4096];
    const int bid = blockIdx.x;            // (b*8+h)*12 + l
    const int bh = bid / 12;
    const int l  = bid - bh * 12;
    const int h  = bh & 7;
    const int t = threadIdx.x, w = t >> 6, lane = t & 63;
    const int lo = lane & 15, hi = lane >> 4;
    const _Float16* vb  = v   + (size_t)bid * ND_;
    const _Float16* ksb = ksT + (size_t)(h*12 + l) * ND_;

    f32x4 acc[2][2] = {};
#pragma unroll 2
    for (int c = 0; c < 8; ++c) {
        const int n0 = w*256 + c*32 + hi*8;
        half8 a0, a1;
#pragma unroll
        for (int j = 0; j < 8; ++j) {
            a0[j] = vb[(size_t)(n0 + j)*32 + lo];
            a1[j] = vb[(size_t)(n0 + j)*32 + 16 + lo];
        }
        half8 b0 = *(const half8*)(ksb + (size_t)lo*1024 + n0);
        half8 b1 = *(const half8*)(ksb + (size_t)(16 + lo)*1024 + n0);
        acc[0][0] = __builtin_amdgcn_mfma_f32_16x16x32_f16(a0, b0, acc[0][0], 0, 0, 0);
        acc[0][1] = __builtin_amdgcn_mfma_f32_16x16x32_f16(a0, b1, acc[0][1], 0, 0, 0);
        acc[1][0] = __builtin_amdgcn_mfma_f32_16x16x32_f16(a1, b0, acc[1][0], 0, 0, 0);
        acc[1][1] = __builtin_amdgcn_mfma_f32_16x16x32_f16(a1, b1, acc[1][1], 0, 0, 0);
    }
#pragma unroll
    for (int m = 0; m < 2; ++m)
#pragma unroll
        for (int xm = 0; xm < 2; ++xm)
#pragma unroll
            for (int reg = 0; reg < 4; ++reg)
                red[w*1024 + (m*16 + hi*4 + reg)*32 + xm*16 + lo] = acc[m][xm][reg];
    __syncthreads();
    const int e = t * 4;
    f32x4 s = *(const f32x4*)&red[e];
    s += *(const f32x4*)&red[1024 + e];
    s += *(const f32x4*)&red[2048 + e];
    s += *(const f32x4*)&red[3072 + e];
    half4 o;
#pragma unroll
    for (int i = 0; i < 4; ++i) o[i] = (_Float16)s[i];
    *(half4*)(kvT + (size_t)bid * 1024 + e) = o;
}

// ---- K3: fused softmax(q)@kvT + final conv; 192-spatial tile ---------------
__global__ __launch_bounds__(512, 2) void k_conv_out(
    const _Float16* __restrict__ q, const _Float16* __restrict__ kvw,
    const _Float16* __restrict__ Cfrag, const float* __restrict__ cbp,
    float* __restrict__ out) {
    __shared__ __align__(16) _Float16 Xt[2][6144];
    __shared__ float Cb[256];

    const int t = threadIdx.x;
    const int bx = blockIdx.x, b = blockIdx.y;
    const int s0 = bx * 192;
    const int n0 = bx * 16;
    const int w = t >> 6, lane = t & 63;
    const int lo = lane & 15, hi = lane >> 4;
    if (t < 64) *(f32x4*)&Cb[t*4] = *(const f32x4*)(cbp + t*4);

    f32x4 acc[4][6] = {};

    const bool pvw = (w < 6);
    const int li0 = w * 2;
    const int qrow = n0 + lo;
    const size_t hstep = (size_t)12 * ND_;
    const _Float16* qb_b = q + (size_t)b * 8 * hstep;
    const _Float16* kv_b = kvw + (size_t)b * 98304;

    half8 hq0 = {}, hq1 = {};
    if (pvw) {
        hq0 = *(const half8*)(qb_b + (size_t)li0 * ND_ + (size_t)qrow*32 + hi*8);
        hq1 = *(const half8*)(qb_b + (size_t)(li0+1) * ND_ + (size_t)qrow*32 + hi*8);
    }

    for (int ph = 0; ph <= 8; ++ph) {
        if (ph < 8 && pvw) {
            half8 nq0 = hq0, nq1 = hq1;
            if (ph < 7) {
                nq0 = *(const half8*)(qb_b + (ph+1)*hstep + (size_t)li0 * ND_ + (size_t)qrow*32 + hi*8);
                nq1 = *(const half8*)(qb_b + (ph+1)*hstep + (size_t)(li0+1) * ND_ + (size_t)qrow*32 + hi*8);
            }
            const _Float16* kvh = kv_b + (size_t)ph * 12288;
            _Float16* Xd = Xt[ph & 1];
#pragma unroll
            for (int sub = 0; sub < 2; ++sub) {
                const half8 hq = sub ? hq1 : hq0;
                const int li = li0 + sub;
                float qv[8];
#pragma unroll
                for (int i = 0; i < 8; ++i) qv[i] = (float)hq[i];
                float m8 = fmaxf(fmaxf(fmaxf(qv[0], qv[1]), fmaxf(qv[2], qv[3])),
                                 fmaxf(fmaxf(qv[4], qv[5]), fmaxf(qv[6], qv[7])));
                m8 = fmaxf(m8, __shfl_xor(m8, 16));
                m8 = fmaxf(m8, __shfl_xor(m8, 32));
                const float mS = m8 * SCALE_;
                float ex[8]; float ssum = 0.f;
#pragma unroll
                for (int i = 0; i < 8; ++i) { ex[i] = __expf(qv[i]*SCALE_ - mS); ssum += ex[i]; }
                ssum += __shfl_xor(ssum, 16);
                ssum += __shfl_xor(ssum, 32);
                const float pin = 1.f / ssum;
                half8 af;
#pragma unroll
                for (int i = 0; i < 8; ++i) af[i] = (_Float16)(ex[i] * pin);
                const half8 b0 = *(const half8*)(kvh + li*1024 + lo*32 + hi*8);
                const half8 b1 = *(const half8*)(kvh + li*1024 + (16+lo)*32 + hi*8);
                f32x4 d0 = {}, d1 = {};
                d0 = __builtin_amdgcn_mfma_f32_16x16x32_f16(af, b0, d0, 0, 0, 0);
                d1 = __builtin_amdgcn_mfma_f32_16x16x32_f16(af, b1, d1, 0, 0, 0);
#pragma unroll
                for (int reg = 0; reg < 4; ++reg) {
                    const int sr = (hi*4 + reg)*12 + li;
                    const int cb_ = (sr >> 4)*64 + (sr & 15);
                    const int ca = cb_ + (lo >> 3)*16;
                    const int cc = cb_ + (2 + (lo >> 3))*16;
                    Xd[fsw(ca)*8 + (lo & 7)] = (_Float16)d0[reg];
                    Xd[fsw(cc)*8 + (lo & 7)] = (_Float16)d1[reg];
                }
            }
            hq0 = nq0; hq1 = nq1;
        }
        if (ph >= 1) {
            const _Float16* Wk = Cfrag + (size_t)(ph - 1) * 8192;
            const _Float16* Xc = Xt[(ph - 1) & 1];
            half8 af2[4], bf[6];
#pragma unroll
            for (int m = 0; m < 4; ++m)
                af2[m] = *(const half8*)(Wk + ((((w>>1)*4 + m)*4 + hi)*16 + lo) * 8);
#pragma unroll
            for (int sf = 0; sf < 6; ++sf) {
                const int rc = ((w & 1)*6 + sf)*64 + hi*16 + lo;
                bf[sf] = *(const half8*)&Xc[fsw(rc)*8];
            }
#pragma unroll
            for (int m = 0; m < 4; ++m)
#pragma unroll
                for (int sf = 0; sf < 6; ++sf)
                    acc[m][sf] = __builtin_amdgcn_mfma_f32_16x16x32_f16(af2[m], bf[sf], acc[m][sf], 0, 0, 0);
        }
        asm volatile("s_waitcnt lgkmcnt(0)" ::: "memory");
        __builtin_amdgcn_s_barrier();
        __builtin_amdgcn_sched_barrier(0);
    }

#pragma unroll
    for (int m = 0; m < 4; ++m) {
        const int o = (w>>1)*64 + m*16 + hi*4;
        const f32x4 bb = *(const f32x4*)&Cb[o];
#pragma unroll
        for (int sf = 0; sf < 6; ++sf) {
            const int s = s0 + (w&1)*96 + sf*16 + lo;
            float* dst = out + (size_t)(b*256 + o)*12288 + s;
#pragma unroll
            for (int i = 0; i < 4; ++i)
                dst[(size_t)i * 12288] = fmaxf(acc[m][sf][i] + bb[i], 0.f);
        }
    }
}

extern "C" void kernel_launch(void* const* d_in, const int* in_sizes, int n_in,
                              void* d_out, int out_size, void* d_ws, size_t ws_size,
                              hipStream_t stream) {
    const float* input = (const float*)d_in[0];
    const float* q_w   = (const float*)d_in[1];
    const float* q_b   = (const float*)d_in[2];
    const float* v_w   = (const float*)d_in[3];
    const float* v_b   = (const float*)d_in[4];
    const float* c_w   = (const float*)d_in[5];
    const float* c_b   = (const float*)d_in[6];
    const float* s_bank= (const float*)d_in[7];
    float* out = (float*)d_out;

    char* ws = (char*)d_ws;
    _Float16* ks16 = (_Float16*)ws;                          // 6,291,456 B (ksT)
    _Float16* qh   = (_Float16*)(ws + 6291456);              // 201,326,592 B
    _Float16* vh   = qh + (size_t)100663296;                 // 201,326,592 B
    _Float16* kvT  = vh + (size_t)100663296;                 // 6,291,456 B
    _Float16* Wfrag= kvT + (size_t)3145728;                  // 262,144 B
    _Float16* Cfrag= Wfrag + (size_t)131072;                 // 131,072 B

    k_prep<<<dim3(96), dim3(256), 0, stream>>>(q_w, v_w, c_w, Wfrag, Cfrag);
    k_key_softmax<<<dim3(HLN_ / 256), dim3(256), 0, stream>>>(s_bank, ks16);
    k_conv_qv<<<dim3(16, 32), dim3(512), 0, stream>>>(input, Wfrag, q_b, v_b, qh, vh);
    k_kv<<<dim3(B_ * H_ * L_), dim3(256), 0, stream>>>(ks16, vh, kvT);
    k_conv_out<<<dim3(64, 32), dim3(512), 0, stream>>>(qh, kvT, Cfrag, c_b, out);
}

// Round 18
// 531.003 us; speedup vs baseline: 1.3669x; 1.3669x over previous
//
#include <hip/hip_runtime.h>

#define B_   32
#define C_   256
#define N_   1024
#define L_   12
#define H_   8
#define DK_  32
#define NL_  12288
#define CNL_ 3145728
#define ND_  32768
#define HLN_ 98304
#define SCALE_ 0.17677669529663687f

typedef _Float16 half8 __attribute__((ext_vector_type(8)));
typedef _Float16 half4 __attribute__((ext_vector_type(4)));
typedef float f32x4 __attribute__((ext_vector_type(4)));

__device__ __forceinline__ int div12(int s) { return (int)(((unsigned)s * 43691u) >> 19); }
// bank-spreading chunk swizzle for conv_out's Xt (bijective, banks spread per instr)
__device__ __forceinline__ int fsw(int c) { return c ^ (((c >> 4) & 1) << 2) ^ ((c >> 6) & 3); }

// ---- P+K0 merged: blocks 0..95 = weight prep; blocks 96..479 = key softmax --
__global__ __launch_bounds__(256) void k_prep_softmax(
    const float* __restrict__ wq, const float* __restrict__ wv,
    const float* __restrict__ cw, const float* __restrict__ sb,
    _Float16* __restrict__ Wfrag, _Float16* __restrict__ Cfrag,
    _Float16* __restrict__ ksT) {
    __shared__ _Float16 smT[32 * 260];
    const int t = threadIdx.x;
    if (blockIdx.x < 96) {
        const int gid = blockIdx.x * 256 + t;         // 24576 total
        if (gid < 16384) {
            const int kb = gid >> 11, r = gid & 2047;
            const int mt = r >> 6, o = (r >> 4) & 3, lo = r & 15;
            const int m = mt * 16 + lo;
            const float* src = (m < 256 ? wq + (size_t)m * 256 : wv + (size_t)(m - 256) * 256)
                               + kb * 32 + o * 8;
            f32x4 a0 = *(const f32x4*)src, a1 = *(const f32x4*)(src + 4);
            half8 h;
#pragma unroll
            for (int i = 0; i < 4; ++i) { h[i] = (_Float16)a0[i]; h[4 + i] = (_Float16)a1[i]; }
            *(half8*)(Wfrag + (size_t)gid * 8) = h;
        } else {
            const int c = gid - 16384;                // < 8192
            const int kb = c >> 10, r = c & 1023;
            const int mt = r >> 6, o = (r >> 4) & 3, lo = r & 15;
            const int m = mt * 16 + lo;
            const float* src = cw + (size_t)m * 256 + kb * 32 + o * 8;
            f32x4 a0 = *(const f32x4*)src, a1 = *(const f32x4*)(src + 4);
            half8 h;
#pragma unroll
            for (int i = 0; i < 4; ++i) { h[i] = (_Float16)a0[i]; h[4 + i] = (_Float16)a1[i]; }
            *(half8*)(Cfrag + (size_t)c * 8) = h;
        }
        return;
    }
    const int bx = blockIdx.x - 96;                   // 0..383
    const int row = bx * 256 + t;
    const f32x4* src = (const f32x4*)(sb + (size_t)row * DK_);
    float v[DK_];
#pragma unroll
    for (int i = 0; i < 8; i++) {
        f32x4 t4 = src[i];
        v[4*i+0] = t4[0]; v[4*i+1] = t4[1]; v[4*i+2] = t4[2]; v[4*i+3] = t4[3];
    }
    float m = v[0];
#pragma unroll
    for (int i = 1; i < DK_; i++) m = fmaxf(m, v[i]);
    float s = 0.f;
#pragma unroll
    for (int i = 0; i < DK_; i++) { v[i] = __expf((v[i] - m) * SCALE_); s += v[i]; }
    const float inv = 1.f / s;
#pragma unroll
    for (int i = 0; i < DK_; i++) smT[i * 260 + t] = (_Float16)(v[i] * inv);
    __syncthreads();
    const int x = t >> 3, off = (t & 7) * 32;
    const int base = bx * 256;
    const int hl = base >> 10, nb = base & 1023;
    _Float16* dst = ksT + (size_t)hl * ND_ + (size_t)x * 1024 + nb + off;
    const _Float16* srcT = &smT[x * 260 + off];
#pragma unroll
    for (int k = 0; k < 4; ++k)
        *(half8*)(dst + k * 8) = *(const half8*)(srcT + k * 8);
}

// ------- K1 (best, R11/R16): merged q+v conv; M=512, W in REGISTERS, S=32 ---
__global__ __launch_bounds__(512, 2) void k_conv_qv(
    const float* __restrict__ x, const _Float16* __restrict__ Wfrag,
    const float* __restrict__ bqp, const float* __restrict__ bvp,
    _Float16* __restrict__ qh, _Float16* __restrict__ vh)
{
    __shared__ __align__(16) _Float16 Xl[2][8192];

    const int t = threadIdx.x;
    const int sgrp = blockIdx.x;            // 0..15
    const int b = blockIdx.y;
    const int sbase = sgrp * 768;
    const int w = t >> 6, lane = t & 63;
    const int lo = lane & 15, hi = lane >> 4;

    half8 af[8][4];
#pragma unroll
    for (int kb = 0; kb < 8; ++kb)
#pragma unroll
        for (int m = 0; m < 4; ++m)
            af[kb][m] = *(const half8*)(Wfrag +
                ((size_t)kb*2048 + (size_t)(w*4 + m)*64 + lane) * 8);

    const float* bsel = (w >= 4) ? bvp : bqp;
    f32x4 bb[4];
#pragma unroll
    for (int m = 0; m < 4; ++m)
        bb[m] = *(const f32x4*)(bsel + ((w & 3)*4 + m)*16 + hi*4);

    const int xch = t >> 1, xsh = (t & 1) * 8;
    const int g = xch >> 3, elem = xch & 7;
    const int wb = g*128 + elem;
    const int sx = xsh ^ ((g & 7) << 1) ^ (xsh >> 3);
    const float* px = x + (size_t)b * CNL_ + (size_t)xch * NL_ + sbase + xsh;

    const int base_r = hi*128 + ((lo ^ (hi*2) ^ ((lo & 8) >> 3)) << 3);

    f32x4 c0 = *(const f32x4*)px,        c1 = *(const f32x4*)(px + 4);
    f32x4 c2 = *(const f32x4*)(px + 16), c3 = *(const f32x4*)(px + 20);
#pragma unroll
    for (int k = 0; k < 4; ++k) {
        Xl[0][wb + (((k  ) ^ sx) << 3)]        = (_Float16)c0[k];
        Xl[0][wb + (((k+4) ^ sx) << 3)]        = (_Float16)c1[k];
        Xl[0][4096 + wb + (((k  ) ^ sx) << 3)] = (_Float16)c2[k];
        Xl[0][4096 + wb + (((k+4) ^ sx) << 3)] = (_Float16)c3[k];
    }
    c0 = *(const f32x4*)(px + 32); c1 = *(const f32x4*)(px + 36);
    c2 = *(const f32x4*)(px + 48); c3 = *(const f32x4*)(px + 52);

    for (int i = 0; i < 24; ++i) {
        asm volatile("s_waitcnt lgkmcnt(0)" ::: "memory");
        __builtin_amdgcn_s_barrier();
        __builtin_amdgcn_sched_barrier(0);
        const _Float16* Xc = Xl[i & 1];
        f32x4 acc[4][2] = {};
#pragma unroll
        for (int kb = 0; kb < 8; ++kb) {
            const int ro = kb*512 + (base_r ^ ((kb & 1) << 6));
            half8 bf0 = *(const half8*)&Xc[ro];
            half8 bf1 = *(const half8*)&Xc[4096 + ro];
#pragma unroll
            for (int m = 0; m < 4; ++m) {
                acc[m][0] = __builtin_amdgcn_mfma_f32_16x16x32_f16(af[kb][m], bf0, acc[m][0], 0, 0, 0);
                acc[m][1] = __builtin_amdgcn_mfma_f32_16x16x32_f16(af[kb][m], bf1, acc[m][1], 0, 0, 0);
            }
        }
        if (i < 23) {
            _Float16* Xn = Xl[(i + 1) & 1];
#pragma unroll
            for (int k = 0; k < 4; ++k) {
                Xn[wb + (((k  ) ^ sx) << 3)]        = (_Float16)c0[k];
                Xn[wb + (((k+4) ^ sx) << 3)]        = (_Float16)c1[k];
                Xn[4096 + wb + (((k  ) ^ sx) << 3)] = (_Float16)c2[k];
                Xn[4096 + wb + (((k+4) ^ sx) << 3)] = (_Float16)c3[k];
            }
            if (i < 22) {
                const float* p = px + (size_t)(i + 2) * 32;
                c0 = *(const f32x4*)p;        c1 = *(const f32x4*)(p + 4);
                c2 = *(const f32x4*)(p + 16); c3 = *(const f32x4*)(p + 20);
            }
        }
#pragma unroll
        for (int u = 0; u < 2; ++u) {
            const int sg = sbase + i*32 + u*16 + lo;
            const int n = div12(sg), l = sg - n*12;
#pragma unroll
            for (int m = 0; m < 4; ++m) {
                const int o = (w*4 + m)*16 + hi*4;
                const int ol = o & 255;
                _Float16* dst0 = (w >= 4) ? vh : qh;
                half4 hh;
#pragma unroll
                for (int r = 0; r < 4; ++r) hh[r] = (_Float16)fmaxf(acc[m][u][r] + bb[m][r], 0.f);
                *(half4*)(dst0 + ((size_t)(b*8 + (ol >> 5))*12 + l)*ND_ + (size_t)n*32 + (ol & 31)) = hh;
            }
        }
    }
}

// ---- K2: kvT[b,h,l][y][x] = sum_n V[n][y]*K[n][x] via MFMA ------------------
__global__ __launch_bounds__(256) void k_kv(const _Float16* __restrict__ ksT,
    const _Float16* __restrict__ v, _Float16* __restrict__ kvT) {
    __shared__ float red[4096];
    const int bid = blockIdx.x;            // (b*8+h)*12 + l
    const int bh = bid / 12;
    const int l  = bid - bh * 12;
    const int h  = bh & 7;
    const int t = threadIdx.x, w = t >> 6, lane = t & 63;
    const int lo = lane & 15, hi = lane >> 4;
    const _Float16* vb  = v   + (size_t)bid * ND_;
    const _Float16* ksb = ksT + (size_t)(h*12 + l) * ND_;

    f32x4 acc[2][2] = {};
#pragma unroll 2
    for (int c = 0; c < 8; ++c) {
        const int n0 = w*256 + c*32 + hi*8;
        half8 a0, a1;
#pragma unroll
        for (int j = 0; j < 8; ++j) {
            a0[j] = vb[(size_t)(n0 + j)*32 + lo];
            a1[j] = vb[(size_t)(n0 + j)*32 + 16 + lo];
        }
        half8 b0 = *(const half8*)(ksb + (size_t)lo*1024 + n0);
        half8 b1 = *(const half8*)(ksb + (size_t)(16 + lo)*1024 + n0);
        acc[0][0] = __builtin_amdgcn_mfma_f32_16x16x32_f16(a0, b0, acc[0][0], 0, 0, 0);
        acc[0][1] = __builtin_amdgcn_mfma_f32_16x16x32_f16(a0, b1, acc[0][1], 0, 0, 0);
        acc[1][0] = __builtin_amdgcn_mfma_f32_16x16x32_f16(a1, b0, acc[1][0], 0, 0, 0);
        acc[1][1] = __builtin_amdgcn_mfma_f32_16x16x32_f16(a1, b1, acc[1][1], 0, 0, 0);
    }
#pragma unroll
    for (int m = 0; m < 2; ++m)
#pragma unroll
        for (int xm = 0; xm < 2; ++xm)
#pragma unroll
            for (int reg = 0; reg < 4; ++reg)
                red[w*1024 + (m*16 + hi*4 + reg)*32 + xm*16 + lo] = acc[m][xm][reg];
    __syncthreads();
    const int e = t * 4;
    f32x4 s = *(const f32x4*)&red[e];
    s += *(const f32x4*)&red[1024 + e];
    s += *(const f32x4*)&red[2048 + e];
    s += *(const f32x4*)&red[3072 + e];
    half4 o;
#pragma unroll
    for (int i = 0; i < 4; ++i) o[i] = (_Float16)s[i];
    *(half4*)(kvT + (size_t)bid * 1024 + e) = o;
}

// ---- K3 (R16-best): fused softmax(q)@kvT + final conv; 192-spatial tile ----
__global__ __launch_bounds__(512, 2) void k_conv_out(
    const _Float16* __restrict__ q, const _Float16* __restrict__ kvw,
    const _Float16* __restrict__ Cfrag, const float* __restrict__ cbp,
    float* __restrict__ out) {
    __shared__ __align__(16) _Float16 Xt[2][6144];
    __shared__ float Cb[256];

    const int t = threadIdx.x;
    const int bx = blockIdx.x, b = blockIdx.y;
    const int s0 = bx * 192;
    const int n0 = bx * 16;
    const int w = t >> 6, lane = t & 63;
    const int lo = lane & 15, hi = lane >> 4;
    if (t < 64) *(f32x4*)&Cb[t*4] = *(const f32x4*)(cbp + t*4);

    f32x4 acc[4][6] = {};

    const bool pvw = (w < 6);
    const int li0 = w * 2;
    const int qrow = n0 + lo;
    const size_t hstep = (size_t)12 * ND_;
    const _Float16* qb_b = q + (size_t)b * 8 * hstep;
    const _Float16* kv_b = kvw + (size_t)b * 98304;

    half8 hq0 = {}, hq1 = {};
    if (pvw) {
        hq0 = *(const half8*)(qb_b + (size_t)li0 * ND_ + (size_t)qrow*32 + hi*8);
        hq1 = *(const half8*)(qb_b + (size_t)(li0+1) * ND_ + (size_t)qrow*32 + hi*8);
    }

    for (int ph = 0; ph <= 8; ++ph) {
        if (ph < 8 && pvw) {
            half8 nq0 = hq0, nq1 = hq1;
            if (ph < 7) {
                nq0 = *(const half8*)(qb_b + (ph+1)*hstep + (size_t)li0 * ND_ + (size_t)qrow*32 + hi*8);
                nq1 = *(const half8*)(qb_b + (ph+1)*hstep + (size_t)(li0+1) * ND_ + (size_t)qrow*32 + hi*8);
            }
            const _Float16* kvh = kv_b + (size_t)ph * 12288;
            _Float16* Xd = Xt[ph & 1];
#pragma unroll
            for (int sub = 0; sub < 2; ++sub) {
                const half8 hq = sub ? hq1 : hq0;
                const int li = li0 + sub;
                float qv[8];
#pragma unroll
                for (int i = 0; i < 8; ++i) qv[i] = (float)hq[i];
                float m8 = fmaxf(fmaxf(fmaxf(qv[0], qv[1]), fmaxf(qv[2], qv[3])),
                                 fmaxf(fmaxf(qv[4], qv[5]), fmaxf(qv[6], qv[7])));
                m8 = fmaxf(m8, __shfl_xor(m8, 16));
                m8 = fmaxf(m8, __shfl_xor(m8, 32));
                const float mS = m8 * SCALE_;
                float ex[8]; float ssum = 0.f;
#pragma unroll
                for (int i = 0; i < 8; ++i) { ex[i] = __expf(qv[i]*SCALE_ - mS); ssum += ex[i]; }
                ssum += __shfl_xor(ssum, 16);
                ssum += __shfl_xor(ssum, 32);
                const float pin = 1.f / ssum;
                half8 af;
#pragma unroll
                for (int i = 0; i < 8; ++i) af[i] = (_Float16)(ex[i] * pin);
                const half8 b0 = *(const half8*)(kvh + li*1024 + lo*32 + hi*8);
                const half8 b1 = *(const half8*)(kvh + li*1024 + (16+lo)*32 + hi*8);
                f32x4 d0 = {}, d1 = {};
                d0 = __builtin_amdgcn_mfma_f32_16x16x32_f16(af, b0, d0, 0, 0, 0);
                d1 = __builtin_amdgcn_mfma_f32_16x16x32_f16(af, b1, d1, 0, 0, 0);
#pragma unroll
                for (int reg = 0; reg < 4; ++reg) {
                    const int sr = (hi*4 + reg)*12 + li;
                    const int cb_ = (sr >> 4)*64 + (sr & 15);
                    const int ca = cb_ + (lo >> 3)*16;
                    const int cc = cb_ + (2 + (lo >> 3))*16;
                    Xd[fsw(ca)*8 + (lo & 7)] = (_Float16)d0[reg];
                    Xd[fsw(cc)*8 + (lo & 7)] = (_Float16)d1[reg];
                }
            }
            hq0 = nq0; hq1 = nq1;
        }
        if (ph >= 1) {
            const _Float16* Wk = Cfrag + (size_t)(ph - 1) * 8192;
            const _Float16* Xc = Xt[(ph - 1) & 1];
            half8 af2[4], bf[6];
#pragma unroll
            for (int m = 0; m < 4; ++m)
                af2[m] = *(const half8*)(Wk + ((((w>>1)*4 + m)*4 + hi)*16 + lo) * 8);
#pragma unroll
            for (int sf = 0; sf < 6; ++sf) {
                const int rc = ((w & 1)*6 + sf)*64 + hi*16 + lo;
                bf[sf] = *(const half8*)&Xc[fsw(rc)*8];
            }
#pragma unroll
            for (int m = 0; m < 4; ++m)
#pragma unroll
                for (int sf = 0; sf < 6; ++sf)
                    acc[m][sf] = __builtin_amdgcn_mfma_f32_16x16x32_f16(af2[m], bf[sf], acc[m][sf], 0, 0, 0);
        }
        asm volatile("s_waitcnt lgkmcnt(0)" ::: "memory");
        __builtin_amdgcn_s_barrier();
        __builtin_amdgcn_sched_barrier(0);
    }

#pragma unroll
    for (int m = 0; m < 4; ++m) {
        const int o = (w>>1)*64 + m*16 + hi*4;
        const f32x4 bb = *(const f32x4*)&Cb[o];
#pragma unroll
        for (int sf = 0; sf < 6; ++sf) {
            const int s = s0 + (w&1)*96 + sf*16 + lo;
            float* dst = out + (size_t)(b*256 + o)*12288 + s;
#pragma unroll
            for (int i = 0; i < 4; ++i)
                dst[(size_t)i * 12288] = fmaxf(acc[m][sf][i] + bb[i], 0.f);
        }
    }
}

extern "C" void kernel_launch(void* const* d_in, const int* in_sizes, int n_in,
                              void* d_out, int out_size, void* d_ws, size_t ws_size,
                              hipStream_t stream) {
    const float* input = (const float*)d_in[0];
    const float* q_w   = (const float*)d_in[1];
    const float* q_b   = (const float*)d_in[2];
    const float* v_w   = (const float*)d_in[3];
    const float* v_b   = (const float*)d_in[4];
    const float* c_w   = (const float*)d_in[5];
    const float* c_b   = (const float*)d_in[6];
    const float* s_bank= (const float*)d_in[7];
    float* out = (float*)d_out;

    char* ws = (char*)d_ws;
    _Float16* ks16 = (_Float16*)ws;                          // 6,291,456 B (ksT)
    _Float16* qh   = (_Float16*)(ws + 6291456);              // 201,326,592 B
    _Float16* vh   = qh + (size_t)100663296;                 // 201,326,592 B
    _Float16* kvT  = vh + (size_t)100663296;                 // 6,291,456 B
    _Float16* Wfrag= kvT + (size_t)3145728;                  // 262,144 B
    _Float16* Cfrag= Wfrag + (size_t)131072;                 // 131,072 B

    k_prep_softmax<<<dim3(96 + HLN_/256), dim3(256), 0, stream>>>(
        q_w, v_w, c_w, s_bank, Wfrag, Cfrag, ks16);
    k_conv_qv<<<dim3(16, 32), dim3(512), 0, stream>>>(input, Wfrag, q_b, v_b, qh, vh);
    k_kv<<<dim3(B_ * H_ * L_), dim3(256), 0, stream>>>(ks16, vh, kvT);
    k_conv_out<<<dim3(64, 32), dim3(512), 0, stream>>>(qh, kvT, Cfrag, c_b, out);
}

// Round 19
// 528.884 us; speedup vs baseline: 1.3723x; 1.0040x over previous
//
#include <hip/hip_runtime.h>

#define B_   32
#define C_   256
#define N_   1024
#define L_   12
#define H_   8
#define DK_  32
#define NL_  12288
#define CNL_ 3145728
#define ND_  32768
#define HLN_ 98304
#define SCALE_ 0.17677669529663687f

typedef _Float16 half8 __attribute__((ext_vector_type(8)));
typedef _Float16 half4 __attribute__((ext_vector_type(4)));
typedef float f32x4 __attribute__((ext_vector_type(4)));

__device__ __forceinline__ int div12(int s) { return (int)(((unsigned)s * 43691u) >> 19); }
// bank-spreading chunk swizzle for conv_out's Xt (bijective, banks spread per instr)
__device__ __forceinline__ int fsw(int c) { return c ^ (((c >> 4) & 1) << 2) ^ ((c >> 6) & 3); }

// ---- P+K0 merged: blocks 0..95 = weight prep; blocks 96..479 = key softmax --
__global__ __launch_bounds__(256) void k_prep_softmax(
    const float* __restrict__ wq, const float* __restrict__ wv,
    const float* __restrict__ cw, const float* __restrict__ sb,
    _Float16* __restrict__ Wfrag, _Float16* __restrict__ Cfrag,
    _Float16* __restrict__ ksT) {
    __shared__ _Float16 smT[32 * 260];
    const int t = threadIdx.x;
    if (blockIdx.x < 96) {
        const int gid = blockIdx.x * 256 + t;         // 24576 total
        if (gid < 16384) {
            const int kb = gid >> 11, r = gid & 2047;
            const int mt = r >> 6, o = (r >> 4) & 3, lo = r & 15;
            const int m = mt * 16 + lo;
            const float* src = (m < 256 ? wq + (size_t)m * 256 : wv + (size_t)(m - 256) * 256)
                               + kb * 32 + o * 8;
            f32x4 a0 = *(const f32x4*)src, a1 = *(const f32x4*)(src + 4);
            half8 h;
#pragma unroll
            for (int i = 0; i < 4; ++i) { h[i] = (_Float16)a0[i]; h[4 + i] = (_Float16)a1[i]; }
            *(half8*)(Wfrag + (size_t)gid * 8) = h;
        } else {
            const int c = gid - 16384;                // < 8192
            const int kb = c >> 10, r = c & 1023;
            const int mt = r >> 6, o = (r >> 4) & 3, lo = r & 15;
            const int m = mt * 16 + lo;
            const float* src = cw + (size_t)m * 256 + kb * 32 + o * 8;
            f32x4 a0 = *(const f32x4*)src, a1 = *(const f32x4*)(src + 4);
            half8 h;
#pragma unroll
            for (int i = 0; i < 4; ++i) { h[i] = (_Float16)a0[i]; h[4 + i] = (_Float16)a1[i]; }
            *(half8*)(Cfrag + (size_t)c * 8) = h;
        }
        return;
    }
    const int bx = blockIdx.x - 96;                   // 0..383
    const int row = bx * 256 + t;
    const f32x4* src = (const f32x4*)(sb + (size_t)row * DK_);
    float v[DK_];
#pragma unroll
    for (int i = 0; i < 8; i++) {
        f32x4 t4 = src[i];
        v[4*i+0] = t4[0]; v[4*i+1] = t4[1]; v[4*i+2] = t4[2]; v[4*i+3] = t4[3];
    }
    float m = v[0];
#pragma unroll
    for (int i = 1; i < DK_; i++) m = fmaxf(m, v[i]);
    float s = 0.f;
#pragma unroll
    for (int i = 0; i < DK_; i++) { v[i] = __expf((v[i] - m) * SCALE_); s += v[i]; }
    const float inv = 1.f / s;
#pragma unroll
    for (int i = 0; i < DK_; i++) smT[i * 260 + t] = (_Float16)(v[i] * inv);
    __syncthreads();
    const int x = t >> 3, off = (t & 7) * 32;
    const int base = bx * 256;
    const int hl = base >> 10, nb = base & 1023;
    _Float16* dst = ksT + (size_t)hl * ND_ + (size_t)x * 1024 + nb + off;
    const _Float16* srcT = &smT[x * 260 + off];
#pragma unroll
    for (int k = 0; k < 4; ++k)
        *(half8*)(dst + k * 8) = *(const half8*)(srcT + k * 8);
}

// ------- K1: merged q+v conv; M=512, W in REGISTERS, S=32/iter --------------
// Reordered iteration: LDS writes for tile i+1 issue RIGHT AFTER the barrier
// (data loaded one iter ago; destination buffer freed by this barrier), so the
// write drain hides under the MFMA phase instead of sitting on the barrier tail.
__global__ __launch_bounds__(512, 2) void k_conv_qv(
    const float* __restrict__ x, const _Float16* __restrict__ Wfrag,
    const float* __restrict__ bqp, const float* __restrict__ bvp,
    _Float16* __restrict__ qh, _Float16* __restrict__ vh)
{
    __shared__ __align__(16) _Float16 Xl[2][8192];

    const int t = threadIdx.x;
    const int sgrp = blockIdx.x;            // 0..15
    const int b = blockIdx.y;
    const int sbase = sgrp * 768;
    const int w = t >> 6, lane = t & 63;
    const int lo = lane & 15, hi = lane >> 4;

    half8 af[8][4];
#pragma unroll
    for (int kb = 0; kb < 8; ++kb)
#pragma unroll
        for (int m = 0; m < 4; ++m)
            af[kb][m] = *(const half8*)(Wfrag +
                ((size_t)kb*2048 + (size_t)(w*4 + m)*64 + lane) * 8);

    const float* bsel = (w >= 4) ? bvp : bqp;
    f32x4 bb[4];
#pragma unroll
    for (int m = 0; m < 4; ++m)
        bb[m] = *(const f32x4*)(bsel + ((w & 3)*4 + m)*16 + hi*4);

    const int xch = t >> 1, xsh = (t & 1) * 8;
    const int g = xch >> 3, elem = xch & 7;
    const int wb = g*128 + elem;
    const int sx = xsh ^ ((g & 7) << 1) ^ (xsh >> 3);
    const float* px = x + (size_t)b * CNL_ + (size_t)xch * NL_ + sbase + xsh;

    const int base_r = hi*128 + ((lo ^ (hi*2) ^ ((lo & 8) >> 3)) << 3);

    f32x4 c0 = *(const f32x4*)px,        c1 = *(const f32x4*)(px + 4);
    f32x4 c2 = *(const f32x4*)(px + 16), c3 = *(const f32x4*)(px + 20);
#pragma unroll
    for (int k = 0; k < 4; ++k) {
        Xl[0][wb + (((k  ) ^ sx) << 3)]        = (_Float16)c0[k];
        Xl[0][wb + (((k+4) ^ sx) << 3)]        = (_Float16)c1[k];
        Xl[0][4096 + wb + (((k  ) ^ sx) << 3)] = (_Float16)c2[k];
        Xl[0][4096 + wb + (((k+4) ^ sx) << 3)] = (_Float16)c3[k];
    }
    c0 = *(const f32x4*)(px + 32); c1 = *(const f32x4*)(px + 36);
    c2 = *(const f32x4*)(px + 48); c3 = *(const f32x4*)(px + 52);

    for (int i = 0; i < 24; ++i) {
        asm volatile("s_waitcnt lgkmcnt(0)" ::: "memory");
        __builtin_amdgcn_s_barrier();
        __builtin_amdgcn_sched_barrier(0);
        // (1) stage tile i+1 into the buffer this barrier just freed
        if (i < 23) {
            _Float16* Xn = Xl[(i + 1) & 1];
#pragma unroll
            for (int k = 0; k < 4; ++k) {
                Xn[wb + (((k  ) ^ sx) << 3)]        = (_Float16)c0[k];
                Xn[wb + (((k+4) ^ sx) << 3)]        = (_Float16)c1[k];
                Xn[4096 + wb + (((k  ) ^ sx) << 3)] = (_Float16)c2[k];
                Xn[4096 + wb + (((k+4) ^ sx) << 3)] = (_Float16)c3[k];
            }
            // (2) issue tile i+2 global loads (land during iter i+1)
            if (i < 22) {
                const float* p = px + (size_t)(i + 2) * 32;
                c0 = *(const f32x4*)p;        c1 = *(const f32x4*)(p + 4);
                c2 = *(const f32x4*)(p + 16); c3 = *(const f32x4*)(p + 20);
            }
        }
        // (3) MFMAs on tile i — writes above drain underneath
        const _Float16* Xc = Xl[i & 1];
        f32x4 acc[4][2] = {};
#pragma unroll
        for (int kb = 0; kb < 8; ++kb) {
            const int ro = kb*512 + (base_r ^ ((kb & 1) << 6));
            half8 bf0 = *(const half8*)&Xc[ro];
            half8 bf1 = *(const half8*)&Xc[4096 + ro];
#pragma unroll
            for (int m = 0; m < 4; ++m) {
                acc[m][0] = __builtin_amdgcn_mfma_f32_16x16x32_f16(af[kb][m], bf0, acc[m][0], 0, 0, 0);
                acc[m][1] = __builtin_amdgcn_mfma_f32_16x16x32_f16(af[kb][m], bf1, acc[m][1], 0, 0, 0);
            }
        }
        // (4) epilogue for tile i: bias + relu + fp16, direct stores
#pragma unroll
        for (int u = 0; u < 2; ++u) {
            const int sg = sbase + i*32 + u*16 + lo;
            const int n = div12(sg), l = sg - n*12;
#pragma unroll
            for (int m = 0; m < 4; ++m) {
                const int o = (w*4 + m)*16 + hi*4;
                const int ol = o & 255;
                _Float16* dst0 = (w >= 4) ? vh : qh;
                half4 hh;
#pragma unroll
                for (int r = 0; r < 4; ++r) hh[r] = (_Float16)fmaxf(acc[m][u][r] + bb[m][r], 0.f);
                *(half4*)(dst0 + ((size_t)(b*8 + (ol >> 5))*12 + l)*ND_ + (size_t)n*32 + (ol & 31)) = hh;
            }
        }
    }
}

// ---- K2: kvT[b,h,l][y][x] = sum_n V[n][y]*K[n][x] via MFMA ------------------
__global__ __launch_bounds__(256) void k_kv(const _Float16* __restrict__ ksT,
    const _Float16* __restrict__ v, _Float16* __restrict__ kvT) {
    __shared__ float red[4096];
    const int bid = blockIdx.x;            // (b*8+h)*12 + l
    const int bh = bid / 12;
    const int l  = bid - bh * 12;
    const int h  = bh & 7;
    const int t = threadIdx.x, w = t >> 6, lane = t & 63;
    const int lo = lane & 15, hi = lane >> 4;
    const _Float16* vb  = v   + (size_t)bid * ND_;
    const _Float16* ksb = ksT + (size_t)(h*12 + l) * ND_;

    f32x4 acc[2][2] = {};
#pragma unroll 2
    for (int c = 0; c < 8; ++c) {
        const int n0 = w*256 + c*32 + hi*8;
        half8 a0, a1;
#pragma unroll
        for (int j = 0; j < 8; ++j) {
            a0[j] = vb[(size_t)(n0 + j)*32 + lo];
            a1[j] = vb[(size_t)(n0 + j)*32 + 16 + lo];
        }
        half8 b0 = *(const half8*)(ksb + (size_t)lo*1024 + n0);
        half8 b1 = *(const half8*)(ksb + (size_t)(16 + lo)*1024 + n0);
        acc[0][0] = __builtin_amdgcn_mfma_f32_16x16x32_f16(a0, b0, acc[0][0], 0, 0, 0);
        acc[0][1] = __builtin_amdgcn_mfma_f32_16x16x32_f16(a0, b1, acc[0][1], 0, 0, 0);
        acc[1][0] = __builtin_amdgcn_mfma_f32_16x16x32_f16(a1, b0, acc[1][0], 0, 0, 0);
        acc[1][1] = __builtin_amdgcn_mfma_f32_16x16x32_f16(a1, b1, acc[1][1], 0, 0, 0);
    }
#pragma unroll
    for (int m = 0; m < 2; ++m)
#pragma unroll
        for (int xm = 0; xm < 2; ++xm)
#pragma unroll
            for (int reg = 0; reg < 4; ++reg)
                red[w*1024 + (m*16 + hi*4 + reg)*32 + xm*16 + lo] = acc[m][xm][reg];
    __syncthreads();
    const int e = t * 4;
    f32x4 s = *(const f32x4*)&red[e];
    s += *(const f32x4*)&red[1024 + e];
    s += *(const f32x4*)&red[2048 + e];
    s += *(const f32x4*)&red[3072 + e];
    half4 o;
#pragma unroll
    for (int i = 0; i < 4; ++i) o[i] = (_Float16)s[i];
    *(half4*)(kvT + (size_t)bid * 1024 + e) = o;
}

// ---- K3 (R16-best): fused softmax(q)@kvT + final conv; 192-spatial tile ----
__global__ __launch_bounds__(512, 2) void k_conv_out(
    const _Float16* __restrict__ q, const _Float16* __restrict__ kvw,
    const _Float16* __restrict__ Cfrag, const float* __restrict__ cbp,
    float* __restrict__ out) {
    __shared__ __align__(16) _Float16 Xt[2][6144];
    __shared__ float Cb[256];

    const int t = threadIdx.x;
    const int bx = blockIdx.x, b = blockIdx.y;
    const int s0 = bx * 192;
    const int n0 = bx * 16;
    const int w = t >> 6, lane = t & 63;
    const int lo = lane & 15, hi = lane >> 4;
    if (t < 64) *(f32x4*)&Cb[t*4] = *(const f32x4*)(cbp + t*4);

    f32x4 acc[4][6] = {};

    const bool pvw = (w < 6);
    const int li0 = w * 2;
    const int qrow = n0 + lo;
    const size_t hstep = (size_t)12 * ND_;
    const _Float16* qb_b = q + (size_t)b * 8 * hstep;
    const _Float16* kv_b = kvw + (size_t)b * 98304;

    half8 hq0 = {}, hq1 = {};
    if (pvw) {
        hq0 = *(const half8*)(qb_b + (size_t)li0 * ND_ + (size_t)qrow*32 + hi*8);
        hq1 = *(const half8*)(qb_b + (size_t)(li0+1) * ND_ + (size_t)qrow*32 + hi*8);
    }

    for (int ph = 0; ph <= 8; ++ph) {
        if (ph < 8 && pvw) {
            half8 nq0 = hq0, nq1 = hq1;
            if (ph < 7) {
                nq0 = *(const half8*)(qb_b + (ph+1)*hstep + (size_t)li0 * ND_ + (size_t)qrow*32 + hi*8);
                nq1 = *(const half8*)(qb_b + (ph+1)*hstep + (size_t)(li0+1) * ND_ + (size_t)qrow*32 + hi*8);
            }
            const _Float16* kvh = kv_b + (size_t)ph * 12288;
            _Float16* Xd = Xt[ph & 1];
#pragma unroll
            for (int sub = 0; sub < 2; ++sub) {
                const half8 hq = sub ? hq1 : hq0;
                const int li = li0 + sub;
                float qv[8];
#pragma unroll
                for (int i = 0; i < 8; ++i) qv[i] = (float)hq[i];
                float m8 = fmaxf(fmaxf(fmaxf(qv[0], qv[1]), fmaxf(qv[2], qv[3])),
                                 fmaxf(fmaxf(qv[4], qv[5]), fmaxf(qv[6], qv[7])));
                m8 = fmaxf(m8, __shfl_xor(m8, 16));
                m8 = fmaxf(m8, __shfl_xor(m8, 32));
                const float mS = m8 * SCALE_;
                float ex[8]; float ssum = 0.f;
#pragma unroll
                for (int i = 0; i < 8; ++i) { ex[i] = __expf(qv[i]*SCALE_ - mS); ssum += ex[i]; }
                ssum += __shfl_xor(ssum, 16);
                ssum += __shfl_xor(ssum, 32);
                const float pin = 1.f / ssum;
                half8 af;
#pragma unroll
                for (int i = 0; i < 8; ++i) af[i] = (_Float16)(ex[i] * pin);
                const half8 b0 = *(const half8*)(kvh + li*1024 + lo*32 + hi*8);
                const half8 b1 = *(const half8*)(kvh + li*1024 + (16+lo)*32 + hi*8);
                f32x4 d0 = {}, d1 = {};
                d0 = __builtin_amdgcn_mfma_f32_16x16x32_f16(af, b0, d0, 0, 0, 0);
                d1 = __builtin_amdgcn_mfma_f32_16x16x32_f16(af, b1, d1, 0, 0, 0);
#pragma unroll
                for (int reg = 0; reg < 4; ++reg) {
                    const int sr = (hi*4 + reg)*12 + li;
                    const int cb_ = (sr >> 4)*64 + (sr & 15);
                    const int ca = cb_ + (lo >> 3)*16;
                    const int cc = cb_ + (2 + (lo >> 3))*16;
                    Xd[fsw(ca)*8 + (lo & 7)] = (_Float16)d0[reg];
                    Xd[fsw(cc)*8 + (lo & 7)] = (_Float16)d1[reg];
                }
            }
            hq0 = nq0; hq1 = nq1;
        }
        if (ph >= 1) {
            const _Float16* Wk = Cfrag + (size_t)(ph - 1) * 8192;
            const _Float16* Xc = Xt[(ph - 1) & 1];
            half8 af2[4], bf[6];
#pragma unroll
            for (int m = 0; m < 4; ++m)
                af2[m] = *(const half8*)(Wk + ((((w>>1)*4 + m)*4 + hi)*16 + lo) * 8);
#pragma unroll
            for (int sf = 0; sf < 6; ++sf) {
                const int rc = ((w & 1)*6 + sf)*64 + hi*16 + lo;
                bf[sf] = *(const half8*)&Xc[fsw(rc)*8];
            }
#pragma unroll
            for (int m = 0; m < 4; ++m)
#pragma unroll
                for (int sf = 0; sf < 6; ++sf)
                    acc[m][sf] = __builtin_amdgcn_mfma_f32_16x16x32_f16(af2[m], bf[sf], acc[m][sf], 0, 0, 0);
        }
        asm volatile("s_waitcnt lgkmcnt(0)" ::: "memory");
        __builtin_amdgcn_s_barrier();
        __builtin_amdgcn_sched_barrier(0);
    }

#pragma unroll
    for (int m = 0; m < 4; ++m) {
        const int o = (w>>1)*64 + m*16 + hi*4;
        const f32x4 bb = *(const f32x4*)&Cb[o];
#pragma unroll
        for (int sf = 0; sf < 6; ++sf) {
            const int s = s0 + (w&1)*96 + sf*16 + lo;
            float* dst = out + (size_t)(b*256 + o)*12288 + s;
#pragma unroll
            for (int i = 0; i < 4; ++i)
                dst[(size_t)i * 12288] = fmaxf(acc[m][sf][i] + bb[i], 0.f);
        }
    }
}

extern "C" void kernel_launch(void* const* d_in, const int* in_sizes, int n_in,
                              void* d_out, int out_size, void* d_ws, size_t ws_size,
                              hipStream_t stream) {
    const float* input = (const float*)d_in[0];
    const float* q_w   = (const float*)d_in[1];
    const float* q_b   = (const float*)d_in[2];
    const float* v_w   = (const float*)d_in[3];
    const float* v_b   = (const float*)d_in[4];
    const float* c_w   = (const float*)d_in[5];
    const float* c_b   = (const float*)d_in[6];
    const float* s_bank= (const float*)d_in[7];
    float* out = (float*)d_out;

    char* ws = (char*)d_ws;
    _Float16* ks16 = (_Float16*)ws;                          // 6,291,456 B (ksT)
    _Float16* qh   = (_Float16*)(ws + 6291456);              // 201,326,592 B
    _Float16* vh   = qh + (size_t)100663296;                 // 201,326,592 B
    _Float16* kvT  = vh + (size_t)100663296;                 // 6,291,456 B
    _Float16* Wfrag= kvT + (size_t)3145728;                  // 262,144 B
    _Float16* Cfrag= Wfrag + (size_t)131072;                 // 131,072 B

    k_prep_softmax<<<dim3(96 + HLN_/256), dim3(256), 0, stream>>>(
        q_w, v_w, c_w, s_bank, Wfrag, Cfrag, ks16);
    k_conv_qv<<<dim3(16, 32), dim3(512), 0, stream>>>(input, Wfrag, q_b, v_b, qh, vh);
    k_kv<<<dim3(B_ * H_ * L_), dim3(256), 0, stream>>>(ks16, vh, kvT);
    k_conv_out<<<dim3(64, 32), dim3(512), 0, stream>>>(qh, kvT, Cfrag, c_b, out);
}

// Round 20
// 515.801 us; speedup vs baseline: 1.4071x; 1.0254x over previous
//
#include <hip/hip_runtime.h>

#define B_   32
#define C_   256
#define N_   1024
#define L_   12
#define H_   8
#define DK_  32
#define NL_  12288
#define CNL_ 3145728
#define ND_  32768
#define HLN_ 98304
#define SCALE_ 0.17677669529663687f

typedef _Float16 half8 __attribute__((ext_vector_type(8)));
typedef _Float16 half4 __attribute__((ext_vector_type(4)));
typedef float f32x4 __attribute__((ext_vector_type(4)));

__device__ __forceinline__ int div12(int s) { return (int)(((unsigned)s * 43691u) >> 19); }
__device__ __forceinline__ int fsw(int c) { return c ^ (((c >> 4) & 1) << 2) ^ ((c >> 6) & 3); }

// ---- P+K0 merged: blocks 0..95 = weight prep; blocks 96..479 = key softmax --
__global__ __launch_bounds__(256) void k_prep_softmax(
    const float* __restrict__ wq, const float* __restrict__ wv,
    const float* __restrict__ cw, const float* __restrict__ sb,
    _Float16* __restrict__ Wfrag, _Float16* __restrict__ Cfrag,
    _Float16* __restrict__ ksT) {
    __shared__ _Float16 smT[32 * 260];
    const int t = threadIdx.x;
    if (blockIdx.x < 96) {
        const int gid = blockIdx.x * 256 + t;
        if (gid < 16384) {
            const int kb = gid >> 11, r = gid & 2047;
            const int mt = r >> 6, o = (r >> 4) & 3, lo = r & 15;
            const int m = mt * 16 + lo;
            const float* src = (m < 256 ? wq + (size_t)m * 256 : wv + (size_t)(m - 256) * 256)
                               + kb * 32 + o * 8;
            f32x4 a0 = *(const f32x4*)src, a1 = *(const f32x4*)(src + 4);
            half8 h;
#pragma unroll
            for (int i = 0; i < 4; ++i) { h[i] = (_Float16)a0[i]; h[4 + i] = (_Float16)a1[i]; }
            *(half8*)(Wfrag + (size_t)gid * 8) = h;
        } else {
            const int c = gid - 16384;
            const int kb = c >> 10, r = c & 1023;
            const int mt = r >> 6, o = (r >> 4) & 3, lo = r & 15;
            const int m = mt * 16 + lo;
            const float* src = cw + (size_t)m * 256 + kb * 32 + o * 8;
            f32x4 a0 = *(const f32x4*)src, a1 = *(const f32x4*)(src + 4);
            half8 h;
#pragma unroll
            for (int i = 0; i < 4; ++i) { h[i] = (_Float16)a0[i]; h[4 + i] = (_Float16)a1[i]; }
            *(half8*)(Cfrag + (size_t)c * 8) = h;
        }
        return;
    }
    const int bx = blockIdx.x - 96;
    const int row = bx * 256 + t;
    const f32x4* src = (const f32x4*)(sb + (size_t)row * DK_);
    float v[DK_];
#pragma unroll
    for (int i = 0; i < 8; i++) {
        f32x4 t4 = src[i];
        v[4*i+0] = t4[0]; v[4*i+1] = t4[1]; v[4*i+2] = t4[2]; v[4*i+3] = t4[3];
    }
    float m = v[0];
#pragma unroll
    for (int i = 1; i < DK_; i++) m = fmaxf(m, v[i]);
    float s = 0.f;
#pragma unroll
    for (int i = 0; i < DK_; i++) { v[i] = __expf((v[i] - m) * SCALE_); s += v[i]; }
    const float inv = 1.f / s;
#pragma unroll
    for (int i = 0; i < DK_; i++) smT[i * 260 + t] = (_Float16)(v[i] * inv);
    __syncthreads();
    const int x = t >> 3, off = (t & 7) * 32;
    const int base = bx * 256;
    const int hl = base >> 10, nb = base & 1023;
    _Float16* dst = ksT + (size_t)hl * ND_ + (size_t)x * 1024 + nb + off;
    const _Float16* srcT = &smT[x * 260 + off];
#pragma unroll
    for (int k = 0; k < 4; ++k)
        *(half8*)(dst + k * 8) = *(const half8*)(srcT + k * 8);
}

// ------- K1: merged q+v conv; M=512, W in REGISTERS, S=32/iter, DEPTH-3 -----
// Loads for tile i+3 issue at iter i (2 iters of flight). Two reg sets by tile
// parity (unroll 2 -> compile-time). LDS writes right after the barrier.
__global__ __launch_bounds__(512, 2) void k_conv_qv(
    const float* __restrict__ x, const _Float16* __restrict__ Wfrag,
    const float* __restrict__ bqp, const float* __restrict__ bvp,
    _Float16* __restrict__ qh, _Float16* __restrict__ vh)
{
    __shared__ __align__(16) _Float16 Xl[2][8192];

    const int t = threadIdx.x;
    const int sgrp = blockIdx.x;            // 0..15
    const int b = blockIdx.y;
    const int sbase = sgrp * 768;
    const int w = t >> 6, lane = t & 63;
    const int lo = lane & 15, hi = lane >> 4;

    half8 af[8][4];
#pragma unroll
    for (int kb = 0; kb < 8; ++kb)
#pragma unroll
        for (int m = 0; m < 4; ++m)
            af[kb][m] = *(const half8*)(Wfrag +
                ((size_t)kb*2048 + (size_t)(w*4 + m)*64 + lane) * 8);

    const float* bsel = (w >= 4) ? bvp : bqp;
    f32x4 bb[4];
#pragma unroll
    for (int m = 0; m < 4; ++m)
        bb[m] = *(const f32x4*)(bsel + ((w & 3)*4 + m)*16 + hi*4);

    const int xch = t >> 1, xsh = (t & 1) * 8;
    const int g = xch >> 3, elem = xch & 7;
    const int wb = g*128 + elem;
    const int sx = xsh ^ ((g & 7) << 1) ^ (xsh >> 3);
    const float* px = x + (size_t)b * CNL_ + (size_t)xch * NL_ + sbase + xsh;

    const int base_r = hi*128 + ((lo ^ (hi*2) ^ ((lo & 8) >> 3)) << 3);

    // prologue: tile0 -> LDS buf0; tile1 -> cB (odd); tile2 -> cA (even)
    {
        f32x4 t0 = *(const f32x4*)px,        t1 = *(const f32x4*)(px + 4);
        f32x4 t2 = *(const f32x4*)(px + 16), t3 = *(const f32x4*)(px + 20);
#pragma unroll
        for (int k = 0; k < 4; ++k) {
            Xl[0][wb + (((k  ) ^ sx) << 3)]        = (_Float16)t0[k];
            Xl[0][wb + (((k+4) ^ sx) << 3)]        = (_Float16)t1[k];
            Xl[0][4096 + wb + (((k  ) ^ sx) << 3)] = (_Float16)t2[k];
            Xl[0][4096 + wb + (((k+4) ^ sx) << 3)] = (_Float16)t3[k];
        }
    }
    f32x4 cB0 = *(const f32x4*)(px + 32), cB1 = *(const f32x4*)(px + 36);
    f32x4 cB2 = *(const f32x4*)(px + 48), cB3 = *(const f32x4*)(px + 52);
    f32x4 cA0 = *(const f32x4*)(px + 64), cA1 = *(const f32x4*)(px + 68);
    f32x4 cA2 = *(const f32x4*)(px + 80), cA3 = *(const f32x4*)(px + 84);

#pragma unroll 2
    for (int i = 0; i < 24; ++i) {
        asm volatile("s_waitcnt lgkmcnt(0)" ::: "memory");
        __builtin_amdgcn_s_barrier();
        __builtin_amdgcn_sched_barrier(0);
        // (1) stage tile i+1 from its parity reg set; reload set with tile i+3
        if (i < 23) {
            _Float16* Xn = Xl[(i + 1) & 1];
            if ((i + 1) & 1) {   // odd tile -> cB
#pragma unroll
                for (int k = 0; k < 4; ++k) {
                    Xn[wb + (((k  ) ^ sx) << 3)]        = (_Float16)cB0[k];
                    Xn[wb + (((k+4) ^ sx) << 3)]        = (_Float16)cB1[k];
                    Xn[4096 + wb + (((k  ) ^ sx) << 3)] = (_Float16)cB2[k];
                    Xn[4096 + wb + (((k+4) ^ sx) << 3)] = (_Float16)cB3[k];
                }
                if (i < 21) {
                    const float* p = px + (size_t)(i + 3) * 32;
                    cB0 = *(const f32x4*)p;        cB1 = *(const f32x4*)(p + 4);
                    cB2 = *(const f32x4*)(p + 16); cB3 = *(const f32x4*)(p + 20);
                }
            } else {             // even tile -> cA
#pragma unroll
                for (int k = 0; k < 4; ++k) {
                    Xn[wb + (((k  ) ^ sx) << 3)]        = (_Float16)cA0[k];
                    Xn[wb + (((k+4) ^ sx) << 3)]        = (_Float16)cA1[k];
                    Xn[4096 + wb + (((k  ) ^ sx) << 3)] = (_Float16)cA2[k];
                    Xn[4096 + wb + (((k+4) ^ sx) << 3)] = (_Float16)cA3[k];
                }
                if (i < 21) {
                    const float* p = px + (size_t)(i + 3) * 32;
                    cA0 = *(const f32x4*)p;        cA1 = *(const f32x4*)(p + 4);
                    cA2 = *(const f32x4*)(p + 16); cA3 = *(const f32x4*)(p + 20);
                }
            }
        }
        // (2) MFMAs on tile i
        const _Float16* Xc = Xl[i & 1];
        f32x4 acc[4][2] = {};
#pragma unroll
        for (int kb = 0; kb < 8; ++kb) {
            const int ro = kb*512 + (base_r ^ ((kb & 1) << 6));
            half8 bf0 = *(const half8*)&Xc[ro];
            half8 bf1 = *(const half8*)&Xc[4096 + ro];
#pragma unroll
            for (int m = 0; m < 4; ++m) {
                acc[m][0] = __builtin_amdgcn_mfma_f32_16x16x32_f16(af[kb][m], bf0, acc[m][0], 0, 0, 0);
                acc[m][1] = __builtin_amdgcn_mfma_f32_16x16x32_f16(af[kb][m], bf1, acc[m][1], 0, 0, 0);
            }
        }
        // (3) epilogue for tile i
#pragma unroll
        for (int u = 0; u < 2; ++u) {
            const int sg = sbase + i*32 + u*16 + lo;
            const int n = div12(sg), l = sg - n*12;
#pragma unroll
            for (int m = 0; m < 4; ++m) {
                const int o = (w*4 + m)*16 + hi*4;
                const int ol = o & 255;
                _Float16* dst0 = (w >= 4) ? vh : qh;
                half4 hh;
#pragma unroll
                for (int r = 0; r < 4; ++r) hh[r] = (_Float16)fmaxf(acc[m][u][r] + bb[m][r], 0.f);
                *(half4*)(dst0 + ((size_t)(b*8 + (ol >> 5))*12 + l)*ND_ + (size_t)n*32 + (ol & 31)) = hh;
            }
        }
    }
}

// ---- K2: kvT via MFMA; ONE WAVE per (b,h,l) — no LDS, no barrier ------------
__global__ __launch_bounds__(256) void k_kv(const _Float16* __restrict__ ksT,
    const _Float16* __restrict__ v, _Float16* __restrict__ kvT) {
    const int t = threadIdx.x;
    const int wv = t >> 6, lane = t & 63;
    const int bid = blockIdx.x * 4 + wv;   // grid 768
    const int bh = bid / 12;
    const int l  = bid - bh * 12;
    const int h  = bh & 7;
    const int lo = lane & 15, hi = lane >> 4;
    const _Float16* vb  = v   + (size_t)bid * ND_;
    const _Float16* ksb = ksT + (size_t)(h*12 + l) * ND_;

    f32x4 acc[2][2] = {};
#pragma unroll 4
    for (int c = 0; c < 32; ++c) {
        const int n0 = c*32 + hi*8;
        half8 a0, a1;
#pragma unroll
        for (int j = 0; j < 8; ++j) {
            a0[j] = vb[(size_t)(n0 + j)*32 + lo];
            a1[j] = vb[(size_t)(n0 + j)*32 + 16 + lo];
        }
        half8 b0 = *(const half8*)(ksb + (size_t)lo*1024 + n0);
        half8 b1 = *(const half8*)(ksb + (size_t)(16 + lo)*1024 + n0);
        acc[0][0] = __builtin_amdgcn_mfma_f32_16x16x32_f16(a0, b0, acc[0][0], 0, 0, 0);
        acc[0][1] = __builtin_amdgcn_mfma_f32_16x16x32_f16(a0, b1, acc[0][1], 0, 0, 0);
        acc[1][0] = __builtin_amdgcn_mfma_f32_16x16x32_f16(a1, b0, acc[1][0], 0, 0, 0);
        acc[1][1] = __builtin_amdgcn_mfma_f32_16x16x32_f16(a1, b1, acc[1][1], 0, 0, 0);
    }
    // direct transposed store: kvT[bid][y][x], y = m*16+hi*4+reg, x = xm*16+lo
    _Float16* dst = kvT + (size_t)bid * 1024;
#pragma unroll
    for (int m = 0; m < 2; ++m)
#pragma unroll
        for (int xm = 0; xm < 2; ++xm)
#pragma unroll
            for (int reg = 0; reg < 4; ++reg)
                dst[(m*16 + hi*4 + reg)*32 + xm*16 + lo] = (_Float16)acc[m][xm][reg];
}

// ---- K3 (R16-best): fused softmax(q)@kvT + final conv; 192-spatial tile ----
__global__ __launch_bounds__(512, 2) void k_conv_out(
    const _Float16* __restrict__ q, const _Float16* __restrict__ kvw,
    const _Float16* __restrict__ Cfrag, const float* __restrict__ cbp,
    float* __restrict__ out) {
    __shared__ __align__(16) _Float16 Xt[2][6144];
    __shared__ float Cb[256];

    const int t = threadIdx.x;
    const int bx = blockIdx.x, b = blockIdx.y;
    const int s0 = bx * 192;
    const int n0 = bx * 16;
    const int w = t >> 6, lane = t & 63;
    const int lo = lane & 15, hi = lane >> 4;
    if (t < 64) *(f32x4*)&Cb[t*4] = *(const f32x4*)(cbp + t*4);

    f32x4 acc[4][6] = {};

    const bool pvw = (w < 6);
    const int li0 = w * 2;
    const int qrow = n0 + lo;
    const size_t hstep = (size_t)12 * ND_;
    const _Float16* qb_b = q + (size_t)b * 8 * hstep;
    const _Float16* kv_b = kvw + (size_t)b * 98304;

    half8 hq0 = {}, hq1 = {};
    if (pvw) {
        hq0 = *(const half8*)(qb_b + (size_t)li0 * ND_ + (size_t)qrow*32 + hi*8);
        hq1 = *(const half8*)(qb_b + (size_t)(li0+1) * ND_ + (size_t)qrow*32 + hi*8);
    }

    for (int ph = 0; ph <= 8; ++ph) {
        if (ph < 8 && pvw) {
            half8 nq0 = hq0, nq1 = hq1;
            if (ph < 7) {
                nq0 = *(const half8*)(qb_b + (ph+1)*hstep + (size_t)li0 * ND_ + (size_t)qrow*32 + hi*8);
                nq1 = *(const half8*)(qb_b + (ph+1)*hstep + (size_t)(li0+1) * ND_ + (size_t)qrow*32 + hi*8);
            }
            const _Float16* kvh = kv_b + (size_t)ph * 12288;
            _Float16* Xd = Xt[ph & 1];
#pragma unroll
            for (int sub = 0; sub < 2; ++sub) {
                const half8 hq = sub ? hq1 : hq0;
                const int li = li0 + sub;
                float qv[8];
#pragma unroll
                for (int i = 0; i < 8; ++i) qv[i] = (float)hq[i];
                float m8 = fmaxf(fmaxf(fmaxf(qv[0], qv[1]), fmaxf(qv[2], qv[3])),
                                 fmaxf(fmaxf(qv[4], qv[5]), fmaxf(qv[6], qv[7])));
                m8 = fmaxf(m8, __shfl_xor(m8, 16));
                m8 = fmaxf(m8, __shfl_xor(m8, 32));
                const float mS = m8 * SCALE_;
                float ex[8]; float ssum = 0.f;
#pragma unroll
                for (int i = 0; i < 8; ++i) { ex[i] = __expf(qv[i]*SCALE_ - mS); ssum += ex[i]; }
                ssum += __shfl_xor(ssum, 16);
                ssum += __shfl_xor(ssum, 32);
                const float pin = 1.f / ssum;
                half8 af;
#pragma unroll
                for (int i = 0; i < 8; ++i) af[i] = (_Float16)(ex[i] * pin);
                const half8 b0 = *(const half8*)(kvh + li*1024 + lo*32 + hi*8);
                const half8 b1 = *(const half8*)(kvh + li*1024 + (16+lo)*32 + hi*8);
                f32x4 d0 = {}, d1 = {};
                d0 = __builtin_amdgcn_mfma_f32_16x16x32_f16(af, b0, d0, 0, 0, 0);
                d1 = __builtin_amdgcn_mfma_f32_16x16x32_f16(af, b1, d1, 0, 0, 0);
#pragma unroll
                for (int reg = 0; reg < 4; ++reg) {
                    const int sr = (hi*4 + reg)*12 + li;
                    const int cb_ = (sr >> 4)*64 + (sr & 15);
                    const int ca = cb_ + (lo >> 3)*16;
                    const int cc = cb_ + (2 + (lo >> 3))*16;
                    Xd[fsw(ca)*8 + (lo & 7)] = (_Float16)d0[reg];
                    Xd[fsw(cc)*8 + (lo & 7)] = (_Float16)d1[reg];
                }
            }
            hq0 = nq0; hq1 = nq1;
        }
        if (ph >= 1) {
            const _Float16* Wk = Cfrag + (size_t)(ph - 1) * 8192;
            const _Float16* Xc = Xt[(ph - 1) & 1];
            half8 af2[4], bf[6];
#pragma unroll
            for (int m = 0; m < 4; ++m)
                af2[m] = *(const half8*)(Wk + ((((w>>1)*4 + m)*4 + hi)*16 + lo) * 8);
#pragma unroll
            for (int sf = 0; sf < 6; ++sf) {
                const int rc = ((w & 1)*6 + sf)*64 + hi*16 + lo;
                bf[sf] = *(const half8*)&Xc[fsw(rc)*8];
            }
#pragma unroll
            for (int m = 0; m < 4; ++m)
#pragma unroll
                for (int sf = 0; sf < 6; ++sf)
                    acc[m][sf] = __builtin_amdgcn_mfma_f32_16x16x32_f16(af2[m], bf[sf], acc[m][sf], 0, 0, 0);
        }
        asm volatile("s_waitcnt lgkmcnt(0)" ::: "memory");
        __builtin_amdgcn_s_barrier();
        __builtin_amdgcn_sched_barrier(0);
    }

#pragma unroll
    for (int m = 0; m < 4; ++m) {
        const int o = (w>>1)*64 + m*16 + hi*4;
        const f32x4 bb = *(const f32x4*)&Cb[o];
#pragma unroll
        for (int sf = 0; sf < 6; ++sf) {
            const int s = s0 + (w&1)*96 + sf*16 + lo;
            float* dst = out + (size_t)(b*256 + o)*12288 + s;
#pragma unroll
            for (int i = 0; i < 4; ++i)
                dst[(size_t)i * 12288] = fmaxf(acc[m][sf][i] + bb[i], 0.f);
        }
    }
}

extern "C" void kernel_launch(void* const* d_in, const int* in_sizes, int n_in,
                              void* d_out, int out_size, void* d_ws, size_t ws_size,
                              hipStream_t stream) {
    const float* input = (const float*)d_in[0];
    const float* q_w   = (const float*)d_in[1];
    const float* q_b   = (const float*)d_in[2];
    const float* v_w   = (const float*)d_in[3];
    const float* v_b   = (const float*)d_in[4];
    const float* c_w   = (const float*)d_in[5];
    const float* c_b   = (const float*)d_in[6];
    const float* s_bank= (const float*)d_in[7];
    float* out = (float*)d_out;

    char* ws = (char*)d_ws;
    _Float16* ks16 = (_Float16*)ws;                          // 6,291,456 B (ksT)
    _Float16* qh   = (_Float16*)(ws + 6291456);              // 201,326,592 B
    _Float16* vh   = qh + (size_t)100663296;                 // 201,326,592 B
    _Float16* kvT  = vh + (size_t)100663296;                 // 6,291,456 B
    _Float16* Wfrag= kvT + (size_t)3145728;                  // 262,144 B
    _Float16* Cfrag= Wfrag + (size_t)131072;                 // 131,072 B

    k_prep_softmax<<<dim3(96 + HLN_/256), dim3(256), 0, stream>>>(
        q_w, v_w, c_w, s_bank, Wfrag, Cfrag, ks16);
    k_conv_qv<<<dim3(16, 32), dim3(512), 0, stream>>>(input, Wfrag, q_b, v_b, qh, vh);
    k_kv<<<dim3(B_ * H_ * L_ / 4), dim3(256), 0, stream>>>(ks16, vh, kvT);
    k_conv_out<<<dim3(64, 32), dim3(512), 0, stream>>>(qh, kvT, Cfrag, c_b, out);
}